// Round 7
// baseline (128.437 us; speedup 1.0000x reference)
//
#include <hip/hip_runtime.h>

#define BB 32
#define NN_ 128
#define NIN 64
#define MH 256
#define MO 64
#define NH 256
#define NO 64
#define EDGES 16256

typedef _Float16 half8 __attribute__((ext_vector_type(8)));   // 8 f16 = 4 VGPRs
typedef __attribute__((ext_vector_type(4))) float f32x4;      // MFMA acc

// ws layout (floats):
//   psb: [B][32][128][8] f16   off 0        = 524288 floats
//   prb: [B][N][256]     f16   off 524288   = 524288 floats
//   w2b: [32][64][8]     f16   off 1048576  = 8192 floats
//   o1b: [256][64]       f16   off 1056768  = 8192 floats
//   o2b: [256][256]      f16   off 1064960  = 32768 floats
//   o3b: [64][256]       f16   off 1097728  = 8192 floats

static __device__ __forceinline__ unsigned short f2h(float f) {
    return __builtin_bit_cast(unsigned short, (_Float16)f);   // v_cvt_f16_f32
}

// pack 8 fp32 -> 8 f16 via 4x v_cvt_pkrtz_f16_f32 (1 inst per pair)
static __device__ __forceinline__ half8 pack8h(float4 f0, float4 f1) {
    uint4 u;
    u.x = __builtin_bit_cast(unsigned, __builtin_amdgcn_cvt_pkrtz(f0.x, f0.y));
    u.y = __builtin_bit_cast(unsigned, __builtin_amdgcn_cvt_pkrtz(f0.z, f0.w));
    u.z = __builtin_bit_cast(unsigned, __builtin_amdgcn_cvt_pkrtz(f1.x, f1.y));
    u.w = __builtin_bit_cast(unsigned, __builtin_amdgcn_cvt_pkrtz(f1.z, f1.w));
    return __builtin_bit_cast(half8, u);
}

// relu(s + p) fully in packed-f16 domain: 4x v_pk_add_f16 + 4x v_pk_max_f16
static __device__ __forceinline__ half8 addrelu(uint4 s, uint4 p) {
    half8 a = __builtin_bit_cast(half8, s) + __builtin_bit_cast(half8, p);
    half8 z = {};
    return __builtin_elementwise_max(a, z);
}

// ---------------------------------------------------------------------------
// Kernel 1: prep (unchanged).
//   blocks 0..255   : fc1 partials via f16 MFMA -> psb/prb
//   blocks 256..319 : W2 -> f16 re-layout w2b[kc4][n][k7]
//   blocks 320..703 : O1/O2/O3 -> f16 casts
// ---------------------------------------------------------------------------
__global__ __launch_bounds__(256) void prep_kernel(
    const float* __restrict__ x, const float* __restrict__ W1,
    const float* __restrict__ b1, const float* __restrict__ W2,
    const float* __restrict__ O1, const float* __restrict__ O2,
    const float* __restrict__ O3,
    unsigned short* __restrict__ psb, unsigned short* __restrict__ prb,
    unsigned short* __restrict__ w2b, unsigned short* __restrict__ o1b,
    unsigned short* __restrict__ o2b, unsigned short* __restrict__ o3b)
{
    int blk = blockIdx.x;
    int t = threadIdx.x;
    if (blk < 256) {
        int row0 = blk << 4;          // 16 consecutive global rows (b = blk>>3)
        int b = blk >> 3;
        int w = t >> 6, lane = t & 63, ml = lane & 15, q = lane >> 4;

        half8 aX[2];
        #pragma unroll
        for (int s = 0; s < 2; ++s) {
            const float* base = x + (size_t)(row0 + ml) * NIN + s * 32 + q * 8;
            aX[s] = pack8h(*(const float4*)base, *(const float4*)(base + 4));
        }

        #pragma unroll
        for (int half = 0; half < 2; ++half) {     // 0 = sender(ps), 1 = recv(pr)
            #pragma unroll
            for (int nt = 0; nt < 4; ++nt) {
                int col = w * 64 + nt * 16 + ml;   // output unit h (0..255)
                const float* wrow = W1 + (size_t)col * (2 * NIN) + half * 64 + q * 8;
                f32x4 acc = (f32x4){0.f, 0.f, 0.f, 0.f};
                #pragma unroll
                for (int s = 0; s < 2; ++s) {
                    half8 bw = pack8h(*(const float4*)(wrow + 32 * s),
                                      *(const float4*)(wrow + 32 * s + 4));
                    acc = __builtin_amdgcn_mfma_f32_16x16x32_f16(aX[s], bw, acc, 0, 0, 0);
                }
                if (half == 0) {
                    #pragma unroll
                    for (int reg = 0; reg < 4; ++reg) {
                        int n = (row0 + q * 4 + reg) & 127;
                        psb[((size_t)(b * 32 + (col >> 3)) * NN_ + n) * 8 + (col & 7)]
                            = f2h(acc[reg]);
                    }
                } else {
                    float bv = b1[col];
                    #pragma unroll
                    for (int reg = 0; reg < 4; ++reg) {
                        int n = (row0 + q * 4 + reg) & 127;
                        prb[((size_t)(b * NN_) + n) * MH + col] = f2h(acc[reg] + bv);
                    }
                }
            }
        }
    } else if (blk < 320) {
        int i = ((blk - 256) << 8) + t;   // 0..16383
        int kc4 = i >> 9, rem = i & 511;
        int n = rem >> 3, k7 = i & 7;
        w2b[i] = f2h(W2[n * MH + kc4 * 8 + k7]);   // w2b[kc4][n][k7] = W2[n][k]
    } else {
        int i = ((blk - 320) << 8) + t;   // 0..98303
        if (i < 16384)       o1b[i]         = f2h(O1[i]);
        else if (i < 81920)  o2b[i - 16384] = f2h(O2[i - 16384]);
        else                 o3b[i - 81920] = f2h(O3[i - 81920]);
    }
}

// ---------------------------------------------------------------------------
// Kernel 2: edge fc2 + segment-sum + node MLP, fused per block.
// Grid 512 x 512 threads (8 waves). Block owns 8 consecutive receivers of
// one batch as 4 sequential receiver-pairs. Wave wv owns senders
// [16*wv,16*wv+16) x 4 n-tiles x 2 receivers -> acc[2][4] = 32 regs.
//
// R6 structure change: the unit loop is now BARRIER-FREE and GLOBAL-FREE.
//  - prL: the block's 8 prb rows staged to LDS once (4 KB); per-kc loads
//    become broadcast ds_read_b128 (16-lane groups hit disjoint bank quads).
//  - redA[4][2][8][64]: per-unit reduce buffers (wave-private writes); the
//    8 in-loop barriers collapse to ONE after the loop + a fused reduce.
//  - redA (16 KB, edge phase) unioned with h1L+h2L (16.9 KB, node phase):
//    total LDS 62.6 KB < 64 KB static limit, 2 blocks/CU.
// R5 law: stage unit-invariant data once (w2L/rtwA/usr). R4 law: keep live
// set < 128 VGPRs (512-thr default cap). R3 law: no __launch_bounds__ 2nd
// arg (caps VGPR = 256/arg -> spill).
// ---------------------------------------------------------------------------
__global__ __launch_bounds__(512) void edge_node_kernel(
    const float* __restrict__ rt, const float* __restrict__ b2,
    const unsigned short* __restrict__ psb, const unsigned short* __restrict__ prb,
    const unsigned short* __restrict__ w2b,
    const unsigned short* __restrict__ o1b, const float* __restrict__ b1o,
    const unsigned short* __restrict__ o2b, const float* __restrict__ b2o,
    const unsigned short* __restrict__ o3b, const float* __restrict__ b3o,
    float* __restrict__ out)
{
    int blk = blockIdx.x;          // 0..511
    int t = threadIdx.x;           // 0..511
    int wv = t >> 6;               // wave 0..7
    int lane = t & 63;
    int ml = lane & 15, q = lane >> 4;

    int b = blk >> 4;              // batch (16 blocks per batch)
    int rbase = (blk & 15) << 3;   // first of this block's 8 receivers

    __shared__ uint4 w2L[2048];            // 32 KB: full W2 tile
    __shared__ float rtwA[4][2][128];      // 4 KB: all 4 units' rt weights
    __shared__ uint4 prL[8][32];           // 4 KB: this block's 8 prb rows
    __shared__ float aggL[16][68];         // rows 0..7 data, 8..15 zero
    __shared__ __align__(16) char uni[17280];   // redA(16K) U h1L+h2L(16.9K)
    typedef float red_t[2][8][64];
    red_t* redA = (red_t*)uni;             // [4][2][8][64], edge phase only
    typedef unsigned short row264[264];
    row264* h1L = (row264*)uni;            // [16][264], node phase only
    row264* h2L = (row264*)(uni + 8448);   // [16][264], node phase only

    // ---- one-time staging (all unit-invariant data) ----
    {
        const uint4* w24 = (const uint4*)w2b;
        #pragma unroll
        for (int i = 0; i < 4; ++i)        // lane-consecutive: conflict-free
            w2L[t + 512 * i] = w24[t + 512 * i];
    }
    if (t < 256) {                         // 8 prb rows -> prL
        int r = t >> 5, c = t & 31;
        prL[r][c] = ((const uint4*)(prb + ((size_t)(b * NN_ + rbase + r)) * MH))[c];
    }
    #pragma unroll
    for (int j = 0; j < 2; ++j) {          // rtw for all 4 units
        int idx = 2 * t + j;               // 0..1023
        int un = idx >> 8, rr = (idx >> 7) & 1, s = idx & 127;
        int r = rbase + un * 2 + rr;
        float v = 0.f;
        if (s != r) {
            int e = r * 127 + s - (s > r ? 1 : 0);
            const float* p = rt + ((size_t)(b * EDGES + e)) * 2;
            v = p[0] + p[1];
        }
        rtwA[un][rr][s] = v;
    }

    // zero-pad rows 8..15 (node MFMA reads 16 rows; only 8 are real)
    aggL[8 + wv][lane] = 0.f;

    float b2c[4];
    #pragma unroll
    for (int nt = 0; nt < 4; ++nt) b2c[nt] = b2[16 * nt + ml];

    // sender fragments: loaded ONCE, live across all 4 units (32 VGPRs)
    int slot = 16 * wv + ml;
    uint4 usr[8];
    {
        const uint4* ps4 = (const uint4*)psb + (size_t)b * (32 * NN_);
        #pragma unroll
        for (int kc = 0; kc < 8; ++kc)
            usr[kc] = ps4[(4 * kc + q) * NN_ + slot];
    }

    __syncthreads();   // staging complete; unit loop is barrier-free

    #pragma unroll 1
    for (int un = 0; un < 4; ++un) {
        f32x4 acc[2][4];   // [receiver][n-tile] = 32 VGPRs
        #pragma unroll
        for (int rr = 0; rr < 2; ++rr)
            #pragma unroll
            for (int nt = 0; nt < 4; ++nt)
                acc[rr][nt] = (f32x4){0.f, 0.f, 0.f, 0.f};

        #pragma unroll
        for (int kc = 0; kc < 8; ++kc) {
            int kc4 = 4 * kc + q;
            uint4 up0 = prL[un * 2][kc4];        // broadcast ds_read
            uint4 up1 = prL[un * 2 + 1][kc4];

            half8 a0 = addrelu(usr[kc], up0);    // r0
            half8 a1 = addrelu(usr[kc], up1);    // r1

            #pragma unroll
            for (int nt = 0; nt < 4; ++nt) {
                half8 bw = __builtin_bit_cast(half8, w2L[kc4 * 64 + 16 * nt + ml]);
                acc[0][nt] = __builtin_amdgcn_mfma_f32_16x16x32_f16(a0, bw, acc[0][nt], 0, 0, 0);
                acc[1][nt] = __builtin_amdgcn_mfma_f32_16x16x32_f16(a1, bw, acc[1][nt], 0, 0, 0);
            }
        }

        // per-wave reduction over its 16 senders (C row = 16*wv + 4*q + reg,
        // C col = 16*nt + ml), cross-q via shfl; wave-private redA write
        #pragma unroll
        for (int rr = 0; rr < 2; ++rr) {
            float colsum[4] = {0.f, 0.f, 0.f, 0.f};
            int srow = 16 * wv + 4 * q;
            #pragma unroll
            for (int reg = 0; reg < 4; ++reg) {
                float rw = rtwA[un][rr][srow + reg];
                #pragma unroll
                for (int nt = 0; nt < 4; ++nt)
                    colsum[nt] += fmaxf(acc[rr][nt][reg] + b2c[nt], 0.f) * rw;
            }
            #pragma unroll
            for (int nt = 0; nt < 4; ++nt) {
                colsum[nt] += __shfl_xor(colsum[nt], 16);
                colsum[nt] += __shfl_xor(colsum[nt], 32);
            }
            if (lane < 16) {
                #pragma unroll
                for (int nt = 0; nt < 4; ++nt)
                    redA[un][rr][wv][16 * nt + ml] = colsum[nt];
            }
        }
    }

    __syncthreads();   // all units' redA complete
    {                  // fused cross-wave reduce: 512 threads = 8 rows x 64
        int row = t >> 6, o = t & 63;
        float s = 0.f;
        #pragma unroll
        for (int w8 = 0; w8 < 8; ++w8) s += redA[row >> 1][row & 1][w8][o];
        aggL[row][o] = s;
    }
    __syncthreads();   // aggL ready; redA dead -> h1L/h2L may reuse uni

    // ------------------------------- node MLP -------------------------------
    half8 aA[2];
    #pragma unroll
    for (int s = 0; s < 2; ++s) {
        const float* base = &aggL[ml][32 * s + q * 8];
        aA[s] = pack8h(*(const float4*)base, *(const float4*)(base + 4));
    }

    // fc1: [16 x 64] @ [64 x 256]  (16 n-tiles over 8 waves)
    #pragma unroll
    for (int nt = 0; nt < 2; ++nt) {
        int ntg = wv * 2 + nt;
        f32x4 acc = (f32x4){0.f, 0.f, 0.f, 0.f};
        #pragma unroll
        for (int s = 0; s < 2; ++s) {
            half8 bw = *(const half8*)(o1b + (size_t)(ntg * 16 + ml) * 64 + 32 * s + q * 8);
            acc = __builtin_amdgcn_mfma_f32_16x16x32_f16(aA[s], bw, acc, 0, 0, 0);
        }
        float bv = b1o[ntg * 16 + ml];
        #pragma unroll
        for (int reg = 0; reg < 4; ++reg)
            h1L[q * 4 + reg][ntg * 16 + ml] = f2h(fmaxf(acc[reg] + bv, 0.f));
    }
    __syncthreads();

    // fc2: [16 x 256] @ [256 x 256]
    half8 aH[8];
    #pragma unroll
    for (int ks = 0; ks < 8; ++ks)
        aH[ks] = *(const half8*)&h1L[ml][32 * ks + q * 8];
    #pragma unroll
    for (int nt = 0; nt < 2; ++nt) {
        int ntg = wv * 2 + nt;
        const unsigned short* wrow = o2b + (size_t)(ntg * 16 + ml) * NH + q * 8;
        f32x4 acc = (f32x4){0.f, 0.f, 0.f, 0.f};
        #pragma unroll
        for (int ks = 0; ks < 8; ++ks) {
            half8 bw = *(const half8*)(wrow + 32 * ks);
            acc = __builtin_amdgcn_mfma_f32_16x16x32_f16(aH[ks], bw, acc, 0, 0, 0);
        }
        float bv = b2o[ntg * 16 + ml];
        #pragma unroll
        for (int reg = 0; reg < 4; ++reg)
            h2L[q * 4 + reg][ntg * 16 + ml] = f2h(fmaxf(acc[reg] + bv, 0.f));
    }
    __syncthreads();

    // fc3: [16 x 256] @ [256 x 64]  (4 n-tiles, waves 0..3)
    if (wv < 4) {
        #pragma unroll
        for (int ks = 0; ks < 8; ++ks)
            aH[ks] = *(const half8*)&h2L[ml][32 * ks + q * 8];
        const unsigned short* wrow = o3b + (size_t)(wv * 16 + ml) * NH + q * 8;
        f32x4 acc = (f32x4){0.f, 0.f, 0.f, 0.f};
        #pragma unroll
        for (int ks = 0; ks < 8; ++ks) {
            half8 bw = *(const half8*)(wrow + 32 * ks);
            acc = __builtin_amdgcn_mfma_f32_16x16x32_f16(aH[ks], bw, acc, 0, 0, 0);
        }
        float bv = b3o[wv * 16 + ml];
        if (q < 2) {   // only rows 0..7 are real
            #pragma unroll
            for (int reg = 0; reg < 4; ++reg)
                out[(size_t)(b * NN_ + rbase + q * 4 + reg) * NO + wv * 16 + ml]
                    = acc[reg] + bv;
        }
    }
}

// ---------------------------------------------------------------------------
extern "C" void kernel_launch(void* const* d_in, const int* in_sizes, int n_in,
                              void* d_out, int out_size, void* d_ws, size_t ws_size,
                              hipStream_t stream) {
    const float* x   = (const float*)d_in[0];
    const float* rt  = (const float*)d_in[3];
    const float* W1  = (const float*)d_in[4];
    const float* b1  = (const float*)d_in[5];
    const float* W2  = (const float*)d_in[6];
    const float* b2  = (const float*)d_in[7];
    const float* O1  = (const float*)d_in[8];
    const float* b1o = (const float*)d_in[9];
    const float* O2  = (const float*)d_in[10];
    const float* b2o = (const float*)d_in[11];
    const float* O3  = (const float*)d_in[12];
    const float* b3o = (const float*)d_in[13];

    float* ws  = (float*)d_ws;
    unsigned short* psb = (unsigned short*)ws;
    unsigned short* prb = (unsigned short*)(ws + 524288);
    unsigned short* w2b = (unsigned short*)(ws + 1048576);
    unsigned short* o1b = (unsigned short*)(ws + 1056768);
    unsigned short* o2b = (unsigned short*)(ws + 1064960);
    unsigned short* o3b = (unsigned short*)(ws + 1097728);
    float* out = (float*)d_out;

    hipLaunchKernelGGL(prep_kernel, dim3(704), dim3(256), 0, stream,
                       x, W1, b1, W2, O1, O2, O3, psb, prb, w2b, o1b, o2b, o3b);
    hipLaunchKernelGGL(edge_node_kernel, dim3(512), dim3(512), 0, stream,
                       rt, b2, psb, prb, w2b, o1b, b1o, o2b, b2o, o3b, b3o, out);
}

// Round 8
// 128.134 us; speedup vs baseline: 1.0024x; 1.0024x over previous
//
#include <hip/hip_runtime.h>

#define BB 32
#define NN_ 128
#define NIN 64
#define MH 256
#define MO 64
#define NH 256
#define NO 64
#define EDGES 16256

typedef _Float16 half8 __attribute__((ext_vector_type(8)));   // 8 f16 = 4 VGPRs
typedef __attribute__((ext_vector_type(4))) float f32x4;      // 16x16 MFMA acc
typedef __attribute__((ext_vector_type(16))) float f32x16;    // 32x32 MFMA acc

// ws layout (floats):
//   psb: [B][32][128][8] f16   off 0        = 524288 floats
//   prb: [B][N][256]     f16   off 524288   = 524288 floats
//   w2b: [32][64][8]     f16   off 1048576  = 8192 floats
//   o1b: [256][64]       f16   off 1056768  = 8192 floats
//   o2b: [256][256]      f16   off 1064960  = 32768 floats
//   o3b: [64][256]       f16   off 1097728  = 8192 floats

static __device__ __forceinline__ unsigned short f2h(float f) {
    return __builtin_bit_cast(unsigned short, (_Float16)f);   // v_cvt_f16_f32
}

// pack 8 fp32 -> 8 f16 via 4x v_cvt_pkrtz_f16_f32 (1 inst per pair)
static __device__ __forceinline__ half8 pack8h(float4 f0, float4 f1) {
    uint4 u;
    u.x = __builtin_bit_cast(unsigned, __builtin_amdgcn_cvt_pkrtz(f0.x, f0.y));
    u.y = __builtin_bit_cast(unsigned, __builtin_amdgcn_cvt_pkrtz(f0.z, f0.w));
    u.z = __builtin_bit_cast(unsigned, __builtin_amdgcn_cvt_pkrtz(f1.x, f1.y));
    u.w = __builtin_bit_cast(unsigned, __builtin_amdgcn_cvt_pkrtz(f1.z, f1.w));
    return __builtin_bit_cast(half8, u);
}

// relu(s + p) fully in packed-f16 domain: 4x v_pk_add_f16 + 4x v_pk_max_f16
static __device__ __forceinline__ half8 addrelu(uint4 s, uint4 p) {
    half8 a = __builtin_bit_cast(half8, s) + __builtin_bit_cast(half8, p);
    half8 z = {};
    return __builtin_elementwise_max(a, z);
}

// ---------------------------------------------------------------------------
// Kernel 1: prep (unchanged).
//   blocks 0..255   : fc1 partials via f16 MFMA -> psb/prb
//   blocks 256..319 : W2 -> f16 re-layout w2b[kc4][n][k7]
//   blocks 320..703 : O1/O2/O3 -> f16 casts
// ---------------------------------------------------------------------------
__global__ __launch_bounds__(256) void prep_kernel(
    const float* __restrict__ x, const float* __restrict__ W1,
    const float* __restrict__ b1, const float* __restrict__ W2,
    const float* __restrict__ O1, const float* __restrict__ O2,
    const float* __restrict__ O3,
    unsigned short* __restrict__ psb, unsigned short* __restrict__ prb,
    unsigned short* __restrict__ w2b, unsigned short* __restrict__ o1b,
    unsigned short* __restrict__ o2b, unsigned short* __restrict__ o3b)
{
    int blk = blockIdx.x;
    int t = threadIdx.x;
    if (blk < 256) {
        int row0 = blk << 4;          // 16 consecutive global rows (b = blk>>3)
        int b = blk >> 3;
        int w = t >> 6, lane = t & 63, ml = lane & 15, q = lane >> 4;

        half8 aX[2];
        #pragma unroll
        for (int s = 0; s < 2; ++s) {
            const float* base = x + (size_t)(row0 + ml) * NIN + s * 32 + q * 8;
            aX[s] = pack8h(*(const float4*)base, *(const float4*)(base + 4));
        }

        #pragma unroll
        for (int half = 0; half < 2; ++half) {     // 0 = sender(ps), 1 = recv(pr)
            #pragma unroll
            for (int nt = 0; nt < 4; ++nt) {
                int col = w * 64 + nt * 16 + ml;   // output unit h (0..255)
                const float* wrow = W1 + (size_t)col * (2 * NIN) + half * 64 + q * 8;
                f32x4 acc = (f32x4){0.f, 0.f, 0.f, 0.f};
                #pragma unroll
                for (int s = 0; s < 2; ++s) {
                    half8 bw = pack8h(*(const float4*)(wrow + 32 * s),
                                      *(const float4*)(wrow + 32 * s + 4));
                    acc = __builtin_amdgcn_mfma_f32_16x16x32_f16(aX[s], bw, acc, 0, 0, 0);
                }
                if (half == 0) {
                    #pragma unroll
                    for (int reg = 0; reg < 4; ++reg) {
                        int n = (row0 + q * 4 + reg) & 127;
                        psb[((size_t)(b * 32 + (col >> 3)) * NN_ + n) * 8 + (col & 7)]
                            = f2h(acc[reg]);
                    }
                } else {
                    float bv = b1[col];
                    #pragma unroll
                    for (int reg = 0; reg < 4; ++reg) {
                        int n = (row0 + q * 4 + reg) & 127;
                        prb[((size_t)(b * NN_) + n) * MH + col] = f2h(acc[reg] + bv);
                    }
                }
            }
        }
    } else if (blk < 320) {
        int i = ((blk - 256) << 8) + t;   // 0..16383
        int kc4 = i >> 9, rem = i & 511;
        int n = rem >> 3, k7 = i & 7;
        w2b[i] = f2h(W2[n * MH + kc4 * 8 + k7]);   // w2b[kc4][n][k7] = W2[n][k]
    } else {
        int i = ((blk - 320) << 8) + t;   // 0..98303
        if (i < 16384)       o1b[i]         = f2h(O1[i]);
        else if (i < 81920)  o2b[i - 16384] = f2h(O2[i - 16384]);
        else                 o3b[i - 81920] = f2h(O3[i - 81920]);
    }
}

// ---------------------------------------------------------------------------
// Kernel 2: edge fc2 + segment-sum + node MLP, fused per block.
// Grid 512 x 512 threads (8 waves). Block owns 8 consecutive receivers of
// one batch as 4 sequential receiver-pairs (units).
//
// R7 change: edge GEMM moved to mfma_f32_32x32x16_f16. 8 waves = 4 m-tiles
// (32 senders) x 2 n-tiles (32 cols); per wave per unit: 16 k-steps x
// {1 bw ds_read_b128 + 2 broadcast up reads + 2 MFMA}. B LDS traffic per
// wave per unit = exactly its 16 KB B-tile (was 32 KB); MFMA instr count
// and LDS read count halved+ (R7 diagnosis: edge loop was LDS-bw bound,
// ~2 MB LDS reads/CU). Fragment layouts follow the verified 16x16x32
// pattern extrapolated (A: row=l&31, k=8*(l>>5)+j; B symmetric; C/D:
// col=lane&31, row=(reg&3)+8*(reg>>2)+4*(lane>>5) [HW-verified]).
// R5 law: stage unit-invariant data once. R4 law: live set < 128 VGPR.
// R3 law: no __launch_bounds__ 2nd arg (caps VGPR=256/arg -> spill).
// ---------------------------------------------------------------------------
__global__ __launch_bounds__(512) void edge_node_kernel(
    const float* __restrict__ rt, const float* __restrict__ b2,
    const unsigned short* __restrict__ psb, const unsigned short* __restrict__ prb,
    const unsigned short* __restrict__ w2b,
    const unsigned short* __restrict__ o1b, const float* __restrict__ b1o,
    const unsigned short* __restrict__ o2b, const float* __restrict__ b2o,
    const unsigned short* __restrict__ o3b, const float* __restrict__ b3o,
    float* __restrict__ out)
{
    int blk = blockIdx.x;          // 0..511
    int t = threadIdx.x;           // 0..511
    int wv = t >> 6;               // wave 0..7
    int lane = t & 63;
    int ml = lane & 15, q = lane >> 4;   // node phase ids
    int l31 = lane & 31, h = lane >> 5;  // edge phase ids
    int mt = wv >> 1;              // m-tile: senders 32mt..32mt+31
    int nt2 = wv & 1;              // n-tile: cols 32nt2..32nt2+31

    int b = blk >> 4;              // batch (16 blocks per batch)
    int rbase = (blk & 15) << 3;   // first of this block's 8 receivers

    __shared__ uint4 w2L[2048];            // 32 KB: full W2 tile
    __shared__ float rtwA[4][2][128];      // 4 KB: all 4 units' rt weights
    __shared__ uint4 prL[8][32];           // 4 KB: this block's 8 prb rows
    __shared__ float aggL[16][68];         // rows 0..7 data, 8..15 zero
    __shared__ __align__(16) char uni[17280];   // redA(8K) U h1L+h2L(16.9K)
    typedef float red_t[2][4][64];
    red_t* redA = (red_t*)uni;             // [4][2][4][64], edge phase only
    typedef unsigned short row264[264];
    row264* h1L = (row264*)uni;            // [16][264], node phase only
    row264* h2L = (row264*)(uni + 8448);   // [16][264], node phase only

    // ---- one-time staging (all unit-invariant data) ----
    {
        const uint4* w24 = (const uint4*)w2b;
        #pragma unroll
        for (int i = 0; i < 4; ++i)        // lane-consecutive: conflict-free
            w2L[t + 512 * i] = w24[t + 512 * i];
    }
    if (t < 256) {                         // 8 prb rows -> prL
        int r = t >> 5, c = t & 31;
        prL[r][c] = ((const uint4*)(prb + ((size_t)(b * NN_ + rbase + r)) * MH))[c];
    }
    #pragma unroll
    for (int j = 0; j < 2; ++j) {          // rtw for all 4 units
        int idx = 2 * t + j;               // 0..1023
        int un = idx >> 8, rr = (idx >> 7) & 1, s = idx & 127;
        int r = rbase + un * 2 + rr;
        float v = 0.f;
        if (s != r) {
            int e = r * 127 + s - (s > r ? 1 : 0);
            const float* p = rt + ((size_t)(b * EDGES + e)) * 2;
            v = p[0] + p[1];
        }
        rtwA[un][rr][s] = v;
    }

    // zero-pad rows 8..15 (node MFMA reads 16 rows; only 8 are real)
    aggL[8 + wv][lane] = 0.f;

    float b2v = b2[32 * nt2 + l31];        // this wave's output-col bias

    // sender fragments: loaded ONCE, live across all 4 units (64 VGPRs).
    // A-layout 32x32x16: lane holds row 32mt+l31, k = 8*(2ks+h)+j.
    uint4 usr[16];
    {
        const uint4* ps4 = (const uint4*)psb + (size_t)b * (32 * NN_);
        #pragma unroll
        for (int ks = 0; ks < 16; ++ks)
            usr[ks] = ps4[(2 * ks + h) * NN_ + 32 * mt + l31];
    }

    __syncthreads();   // staging complete; unit loop is barrier-free

    #pragma unroll 1
    for (int un = 0; un < 4; ++un) {
        f32x16 acc0 = {0.f,0.f,0.f,0.f,0.f,0.f,0.f,0.f,
                       0.f,0.f,0.f,0.f,0.f,0.f,0.f,0.f};
        f32x16 acc1 = acc0;

        #pragma unroll
        for (int ks = 0; ks < 16; ++ks) {
            uint4 up0 = prL[un * 2][2 * ks + h];       // broadcast (2 addrs)
            uint4 up1 = prL[un * 2 + 1][2 * ks + h];
            half8 a0 = addrelu(usr[ks], up0);          // r0 A-fragment
            half8 a1 = addrelu(usr[ks], up1);          // r1 A-fragment
            half8 bw = __builtin_bit_cast(half8,
                           w2L[(2 * ks + h) * 64 + 32 * nt2 + l31]);
            acc0 = __builtin_amdgcn_mfma_f32_32x32x16_f16(a0, bw, acc0, 0, 0, 0);
            acc1 = __builtin_amdgcn_mfma_f32_32x32x16_f16(a1, bw, acc1, 0, 0, 0);
        }

        // rtw-weighted column reduction. C/D: col = 32nt2+l31,
        // row = 32mt + (reg&3) + 8*(reg>>2) + 4h  (16 rows/lane, h-partition)
        float cs0 = 0.f, cs1 = 0.f;
        #pragma unroll
        for (int reg = 0; reg < 16; ++reg) {
            int row = 32 * mt + (reg & 3) + 8 * (reg >> 2) + 4 * h;
            cs0 += fmaxf(acc0[reg] + b2v, 0.f) * rtwA[un][0][row];
            cs1 += fmaxf(acc1[reg] + b2v, 0.f) * rtwA[un][1][row];
        }
        cs0 += __shfl_xor(cs0, 32);        // combine h-halves (same col)
        cs1 += __shfl_xor(cs1, 32);
        if (lane < 32) {
            redA[un][0][mt][32 * nt2 + l31] = cs0;
            redA[un][1][mt][32 * nt2 + l31] = cs1;
        }
    }

    __syncthreads();   // all units' redA complete
    {                  // fused cross-wave reduce: 512 threads = 8 rows x 64
        int row = t >> 6, o = t & 63;
        float s = 0.f;
        #pragma unroll
        for (int m4 = 0; m4 < 4; ++m4) s += redA[row >> 1][row & 1][m4][o];
        aggL[row][o] = s;
    }
    __syncthreads();   // aggL ready; redA dead -> h1L/h2L may reuse uni

    // ------------------------------- node MLP -------------------------------
    half8 aA[2];
    #pragma unroll
    for (int s = 0; s < 2; ++s) {
        const float* base = &aggL[ml][32 * s + q * 8];
        aA[s] = pack8h(*(const float4*)base, *(const float4*)(base + 4));
    }

    // fc1: [16 x 64] @ [64 x 256]  (16 n-tiles over 8 waves)
    #pragma unroll
    for (int nt = 0; nt < 2; ++nt) {
        int ntg = wv * 2 + nt;
        f32x4 acc = (f32x4){0.f, 0.f, 0.f, 0.f};
        #pragma unroll
        for (int s = 0; s < 2; ++s) {
            half8 bw = *(const half8*)(o1b + (size_t)(ntg * 16 + ml) * 64 + 32 * s + q * 8);
            acc = __builtin_amdgcn_mfma_f32_16x16x32_f16(aA[s], bw, acc, 0, 0, 0);
        }
        float bv = b1o[ntg * 16 + ml];
        #pragma unroll
        for (int reg = 0; reg < 4; ++reg)
            h1L[q * 4 + reg][ntg * 16 + ml] = f2h(fmaxf(acc[reg] + bv, 0.f));
    }
    __syncthreads();

    // fc2: [16 x 256] @ [256 x 256]
    half8 aH[8];
    #pragma unroll
    for (int ks = 0; ks < 8; ++ks)
        aH[ks] = *(const half8*)&h1L[ml][32 * ks + q * 8];
    #pragma unroll
    for (int nt = 0; nt < 2; ++nt) {
        int ntg = wv * 2 + nt;
        const unsigned short* wrow = o2b + (size_t)(ntg * 16 + ml) * NH + q * 8;
        f32x4 acc = (f32x4){0.f, 0.f, 0.f, 0.f};
        #pragma unroll
        for (int ks = 0; ks < 8; ++ks) {
            half8 bw = *(const half8*)(wrow + 32 * ks);
            acc = __builtin_amdgcn_mfma_f32_16x16x32_f16(aH[ks], bw, acc, 0, 0, 0);
        }
        float bv = b2o[ntg * 16 + ml];
        #pragma unroll
        for (int reg = 0; reg < 4; ++reg)
            h2L[q * 4 + reg][ntg * 16 + ml] = f2h(fmaxf(acc[reg] + bv, 0.f));
    }
    __syncthreads();

    // fc3: [16 x 256] @ [256 x 64]  (4 n-tiles, waves 0..3)
    if (wv < 4) {
        #pragma unroll
        for (int ks = 0; ks < 8; ++ks)
            aH[ks] = *(const half8*)&h2L[ml][32 * ks + q * 8];
        const unsigned short* wrow = o3b + (size_t)(wv * 16 + ml) * NH + q * 8;
        f32x4 acc = (f32x4){0.f, 0.f, 0.f, 0.f};
        #pragma unroll
        for (int ks = 0; ks < 8; ++ks) {
            half8 bw = *(const half8*)(wrow + 32 * ks);
            acc = __builtin_amdgcn_mfma_f32_16x16x32_f16(aH[ks], bw, acc, 0, 0, 0);
        }
        float bv = b3o[wv * 16 + ml];
        if (q < 2) {   // only rows 0..7 are real
            #pragma unroll
            for (int reg = 0; reg < 4; ++reg)
                out[(size_t)(b * NN_ + rbase + q * 4 + reg) * NO + wv * 16 + ml]
                    = acc[reg] + bv;
        }
    }
}

// ---------------------------------------------------------------------------
extern "C" void kernel_launch(void* const* d_in, const int* in_sizes, int n_in,
                              void* d_out, int out_size, void* d_ws, size_t ws_size,
                              hipStream_t stream) {
    const float* x   = (const float*)d_in[0];
    const float* rt  = (const float*)d_in[3];
    const float* W1  = (const float*)d_in[4];
    const float* b1  = (const float*)d_in[5];
    const float* W2  = (const float*)d_in[6];
    const float* b2  = (const float*)d_in[7];
    const float* O1  = (const float*)d_in[8];
    const float* b1o = (const float*)d_in[9];
    const float* O2  = (const float*)d_in[10];
    const float* b2o = (const float*)d_in[11];
    const float* O3  = (const float*)d_in[12];
    const float* b3o = (const float*)d_in[13];

    float* ws  = (float*)d_ws;
    unsigned short* psb = (unsigned short*)ws;
    unsigned short* prb = (unsigned short*)(ws + 524288);
    unsigned short* w2b = (unsigned short*)(ws + 1048576);
    unsigned short* o1b = (unsigned short*)(ws + 1056768);
    unsigned short* o2b = (unsigned short*)(ws + 1064960);
    unsigned short* o3b = (unsigned short*)(ws + 1097728);
    float* out = (float*)d_out;

    hipLaunchKernelGGL(prep_kernel, dim3(704), dim3(256), 0, stream,
                       x, W1, b1, W2, O1, O2, O3, psb, prb, w2b, o1b, o2b, o3b);
    hipLaunchKernelGGL(edge_node_kernel, dim3(512), dim3(512), 0, stream,
                       rt, b2, psb, prb, w2b, o1b, b1o, o2b, b2o, o3b, b3o, out);
}